// Round 13
// baseline (301.806 us; speedup 1.0000x reference)
//
#include <hip/hip_runtime.h>

#define HID 1024
#define NH 16
#define HD 64
#define BB 2
#define LL 2048
#define GC 143   // number of global-summary columns
#define GP 192   // padded global columns (3 tiles of 64)
#define AMT_PER_B 2240  // 192 global slots + 16 windows * 128 local slots

typedef __attribute__((ext_vector_type(8))) __bf16 bf16x8;
typedef __attribute__((ext_vector_type(4))) float f32x4;
typedef __attribute__((ext_vector_type(4))) int i32x4;
typedef __attribute__((ext_vector_type(2))) unsigned long long u64x2;

__device__ __forceinline__ void gload_lds16(const void* g, void* l) {
  __builtin_amdgcn_global_load_lds((const __attribute__((address_space(1))) void*)g,
                                   (__attribute__((address_space(3))) void*)l, 16, 0, 0);
}

__device__ __forceinline__ unsigned int cvtpk(float lo, float hi) {
  unsigned int r;
  asm("v_cvt_pk_bf16_f32 %0, %1, %2" : "=v"(r) : "v"(lo), "v"(hi));
  return r;
}

// V^T A-fragment under the permuted formal-k: two 8B LDS reads (swizzled granules)
__device__ __forceinline__ bf16x8 vfrag(const char* vbase, int r, int gA, int gB,
                                        int half) {
  unsigned long long lo =
      *(const unsigned long long*)(vbase + r * 128 + ((gA ^ (r & 7)) << 4) + half);
  unsigned long long hi =
      *(const unsigned long long*)(vbase + r * 128 + ((gB ^ (r & 7)) << 4) + half);
  u64x2 u;
  u[0] = lo;
  u[1] = hi;
  return __builtin_bit_cast(bf16x8, u);
}

// ------- kernel 0: fused prep (cvt_hs | cvt_wt | zero+setup | amt table) -------
__global__ __launch_bounds__(256) void prep_kernel(
    const float* __restrict__ hs, __bf16* __restrict__ hsb,
    const float* __restrict__ Wq, const float* __restrict__ Wk,
    const float* __restrict__ Wv, __bf16* __restrict__ wtb,
    const float* __restrict__ amask, unsigned int* __restrict__ zbase,
    float* __restrict__ amt) {
  int bx = blockIdx.x;
  int t = threadIdx.x;
  if (bx < 2048) {
    // ---- hidden_states fp32 -> bf16 ----
    int i = bx * 256 + t;
    const float4* src = (const float4*)hs;
    float4 a = src[2 * i], b = src[2 * i + 1];
    bf16x8 v;
    v[0] = (__bf16)a.x; v[1] = (__bf16)a.y; v[2] = (__bf16)a.z; v[3] = (__bf16)a.w;
    v[4] = (__bf16)b.x; v[5] = (__bf16)b.y; v[6] = (__bf16)b.z; v[7] = (__bf16)b.w;
    ((bf16x8*)hsb)[i] = v;
  } else if (bx < 2048 + 768) {
    // ---- W [k][n] fp32 -> Wt [n][k] bf16 ----
    int z3 = bx - 2048;
    int kt = z3 & 15, nt = (z3 >> 4) & 15, z = z3 >> 8;
    const float* w = (z == 0) ? Wq : (z == 1) ? Wk : Wv;
    __bf16* dst = wtb + (size_t)z * HID * HID;
    __shared__ __bf16 tile[64][66];
    int cr = t & 63, rr = t >> 6;
#pragma unroll
    for (int it = 0; it < 16; it++) {
      int r = it * 4 + rr;
      tile[cr][r] = (__bf16)w[(size_t)(kt * 64 + r) * HID + nt * 64 + cr];
    }
    __syncthreads();
#pragma unroll
    for (int it = 0; it < 16; it++) {
      int r = it * 4 + rr;
      dst[(size_t)(nt * 64 + r) * HID + kt * 64 + cr] = tile[r][cr];
    }
  } else if (bx < 2048 + 768 + 1536) {
    // ---- zero compact K/V buffers ----
    int i = (bx - 2816) * 256 + t;  // 1536 blocks -> 393216 dwords
    zbase[i] = 0u;
  } else {
    // ---- combined additive softmax table: clip(s) + amt = ready for exp ----
    int idx = (bx - 4352) * 256 + t;
    if (idx < BB * AMT_PER_B) {
      int b = idx / AMT_PER_B, r = idx % AMT_PER_B;
      float val;
      if (r < GP) {
        int k = r / 9, j = r - 9 * k;
        val = (r < GC) ? (amask[b * LL + 120 + 128 * k + j] - 20.f) : -1e5f;
      } else {
        int r2 = r - GP;
        int w = r2 >> 7, off = r2 & 127;
        bool gcol = (off >= 120) || (off == 0 && w != 0);
        val = gcol ? -1e5f : (amask[b * LL + w * 128 + off] - 20.f);
      }
      amt[idx] = val;
    }
  }
}

// ---------------- kernel 1: QKV GEMM (bf16 MFMA, 128x128x64) ----------------
// which==2 (V) uses swapped MFMA operands -> transposed C-frag -> the vtb
// ([d][l]) store becomes coalesced along l (identical values bitwise).
__global__ __launch_bounds__(256, 4) void qkv_gemm_kernel(
    const __bf16* __restrict__ hsb, const __bf16* __restrict__ wtb,
    const float* __restrict__ bq, const float* __restrict__ bk,
    const float* __restrict__ bv, __bf16* __restrict__ qb,
    __bf16* __restrict__ kkb, __bf16* __restrict__ vtb,
    __bf16* __restrict__ kgb, __bf16* __restrict__ vgb) {
  int nt = blockIdx.x, mt = blockIdx.y, which = blockIdx.z;
  const __bf16* wt = wtb + (size_t)which * HID * HID;
  const float* bias = (which == 0) ? bq : (which == 1) ? bk : bv;

  __shared__ __bf16 a_lds[128 * 64];
  __shared__ __bf16 b_lds[128 * 64];

  int tid = threadIdx.x;
  int wave = tid >> 6, lane = tid & 63;
  int wm = wave >> 1, wn = wave & 1;
  int lrow = lane & 15, lgr = lane >> 4, g = lane & 7;

  f32x4 acc[4][4];
#pragma unroll
  for (int i = 0; i < 4; i++)
#pragma unroll
    for (int j = 0; j < 4; j++) acc[i][j] = f32x4{0.f, 0.f, 0.f, 0.f};

  for (int kk = 0; kk < HID; kk += 64) {
#pragma unroll
    for (int i = 0; i < 4; i++) {
      int r = (wave * 4 + i) * 8 + (lane >> 3);
      int gs = (g ^ (r & 7)) * 8;
      gload_lds16(hsb + (size_t)(mt * 128 + r) * HID + kk + gs,
                  &a_lds[(wave * 4 + i) * 512]);
      gload_lds16(wt + (size_t)(nt * 128 + r) * HID + kk + gs,
                  &b_lds[(wave * 4 + i) * 512]);
    }
    __syncthreads();
#pragma unroll
    for (int kf = 0; kf < 2; kf++) {
      bf16x8 af[4], bfr[4];
#pragma unroll
      for (int mr = 0; mr < 4; mr++) {
        int row = wm * 64 + mr * 16 + lrow;
        af[mr] = *(const bf16x8*)((const char*)a_lds + row * 128 +
                                  ((kf * 64 + lgr * 16) ^ ((row & 7) << 4)));
      }
#pragma unroll
      for (int nr = 0; nr < 4; nr++) {
        int row = wn * 64 + nr * 16 + lrow;
        bfr[nr] = *(const bf16x8*)((const char*)b_lds + row * 128 +
                                   ((kf * 64 + lgr * 16) ^ ((row & 7) << 4)));
      }
      if (which != 2) {
#pragma unroll
        for (int mr = 0; mr < 4; mr++)
#pragma unroll
          for (int nr = 0; nr < 4; nr++)
            acc[mr][nr] = __builtin_amdgcn_mfma_f32_16x16x32_bf16(
                af[mr], bfr[nr], acc[mr][nr], 0, 0, 0);
      } else {
        // swapped operands: C-frag row <-> n (d), col <-> m (l)
#pragma unroll
        for (int mr = 0; mr < 4; mr++)
#pragma unroll
          for (int nr = 0; nr < 4; nr++)
            acc[mr][nr] = __builtin_amdgcn_mfma_f32_16x16x32_bf16(
                bfr[nr], af[mr], acc[mr][nr], 0, 0, 0);
      }
    }
    __syncthreads();
  }

  if (which != 2) {
    // epilogue Q/K: bias, (Q: x0.125), scatter to [b,h,l,d] (+ K compacts)
#pragma unroll
    for (int nr = 0; nr < 4; nr++) {
      int n = nt * 128 + wn * 64 + nr * 16 + lrow;
      float bsv = bias[n];
      int hh = n >> 6, d = n & 63;
#pragma unroll
      for (int mr = 0; mr < 4; mr++) {
#pragma unroll
        for (int reg = 0; reg < 4; reg++) {
          int m = mt * 128 + wm * 64 + mr * 16 + lgr * 4 + reg;
          int bidx = m >> 11, l = m & 2047;
          float val = acc[mr][nr][reg] + bsv;
          int c7 = l & 127;
          bool isg = (c7 >= 120) || (c7 == 0 && l != 0);
          int cidx = (c7 >= 120) ? ((l >> 7) * 9 + (c7 - 120)) : (((l >> 7) - 1) * 9 + 8);
          if (which == 0) {
            val *= 0.125f;  // fold 1/sqrt(64) into Q (exact pow2)
            qb[((size_t)(bidx * NH + hh) * LL + l) * HD + d] = (__bf16)val;
          } else {
            __bf16 bv16 = (__bf16)val;
            kkb[((size_t)(bidx * NH + hh) * LL + l) * HD + d] = bv16;
            if (isg) kgb[((size_t)(bidx * NH + hh) * GP + cidx) * HD + d] = bv16;
          }
        }
      }
    }
  } else {
    // epilogue V (transposed frag): row=(lgr*4+reg)<->n, col=lrow<->m
    // vtb[d][l]: 16 lrow-lanes write contiguous l -> coalesced
#pragma unroll
    for (int nr = 0; nr < 4; nr++) {
#pragma unroll
      for (int reg = 0; reg < 4; reg++) {
        int n = nt * 128 + wn * 64 + nr * 16 + lgr * 4 + reg;
        float bsv = bias[n];
        int hh = n >> 6, d = n & 63;
#pragma unroll
        for (int mr = 0; mr < 4; mr++) {
          int m = mt * 128 + wm * 64 + mr * 16 + lrow;
          int bidx = m >> 11, l = m & 2047;
          float val = acc[mr][nr][reg] + bsv;
          __bf16 bv16 = (__bf16)val;
          size_t bh = (size_t)(bidx * NH + hh);
          vtb[(bh * HD + d) * LL + l] = bv16;
          int c7 = l & 127;
          bool isg = (c7 >= 120) || (c7 == 0 && l != 0);
          if (isg) {
            int cidx = (c7 >= 120) ? ((l >> 7) * 9 + (c7 - 120))
                                   : (((l >> 7) - 1) * 9 + 8);
            vgb[(bh * HD + d) * GP + cidx] = bv16;
          }
        }
      }
    }
  }
}

// ---- kernel 2: attention, transposed-output, 2 q-groups/wave, ZERO-shuffle PV.
// (unchanged from round 10)
__global__ __launch_bounds__(256, 4) void attn_kernel(
    const __bf16* __restrict__ qb, const __bf16* __restrict__ kkb,
    const __bf16* __restrict__ vtb, const __bf16* __restrict__ kgb,
    const __bf16* __restrict__ vgb, const float* __restrict__ amt,
    float* __restrict__ out) {
  __shared__ __bf16 kbuf[2][64 * 64];
  __shared__ __bf16 vbuf[2][64 * 64];

  int qt = blockIdx.x, hh = blockIdx.y, b = blockIdx.z;
  int tid = threadIdx.x, wave = tid >> 6, lane = tid & 63;
  int lrow = lane & 15, lgr = lane >> 4, g = lane & 7;

  const __bf16* qbh = qb + (size_t)(b * NH + hh) * LL * HD;
  const __bf16* kbh = kkb + (size_t)(b * NH + hh) * LL * HD;
  const __bf16* vth = vtb + (size_t)(b * NH + hh) * HD * LL;
  const __bf16* kgh = kgb + (size_t)(b * NH + hh) * GP * HD;
  const __bf16* vgh = vgb + (size_t)(b * NH + hh) * HD * GP;

  int shift = (qt == 16) ? 0 : 1;
  int qt2 = (qt == 16) ? 0 : qt;
  int W = qt2 * 128;
  const float* amt_b = amt + b * AMT_PER_B;
  const float* amt_l = amt_b + GP + qt2 * 128;

  int qrowA = qt2 * 128 + shift + wave * 32 + lrow;  // group A q-row
  int qrowB = qrowA + 16;                            // group B q-row
  int qldA = (qrowA > LL - 1) ? (LL - 1) : qrowA;
  int qldB = (qrowB > LL - 1) ? (LL - 1) : qrowB;
  bf16x8 qA0 = *(const bf16x8*)(qbh + (size_t)qldA * HD + lgr * 8);
  bf16x8 qA1 = *(const bf16x8*)(qbh + (size_t)qldA * HD + 32 + lgr * 8);
  bf16x8 qB0 = *(const bf16x8*)(qbh + (size_t)qldB * HD + lgr * 8);
  bf16x8 qB1 = *(const bf16x8*)(qbh + (size_t)qldB * HD + 32 + lgr * 8);

  // V-frag granule ids under sigma (fixed per lane)
  int g0 = lgr >> 1, half = (lgr & 1) * 8;

  float lA = 0.f, lB = 0.f;
  f32x4 oA[4], oB[4];
#pragma unroll
  for (int i = 0; i < 4; i++) {
    oA[i] = f32x4{0.f, 0.f, 0.f, 0.f};
    oB[i] = f32x4{0.f, 0.f, 0.f, 0.f};
  }

#define STAGE(IT, BI)                                                     \
  do {                                                                    \
    const __bf16 *ks_, *vs_;                                              \
    int vst_;                                                             \
    if ((IT) < 3) {                                                       \
      ks_ = kgh + (size_t)((IT)*64) * HD;                                 \
      vs_ = vgh + (IT)*64;                                                \
      vst_ = GP;                                                          \
    } else {                                                              \
      int cb_ = W + ((IT)-3) * 64;                                        \
      ks_ = kbh + (size_t)cb_ * HD;                                       \
      vs_ = vth + cb_;                                                    \
      vst_ = LL;                                                          \
    }                                                                     \
    _Pragma("unroll")                                                     \
    for (int i_ = 0; i_ < 2; i_++) {                                      \
      int r_ = (wave * 2 + i_) * 8 + (lane >> 3);                         \
      int gs_ = (g ^ (r_ & 7)) * 8;                                       \
      gload_lds16(ks_ + (size_t)r_ * HD + gs_, &kbuf[BI][(wave * 2 + i_) * 512]); \
      gload_lds16(vs_ + (size_t)r_ * vst_ + gs_, &vbuf[BI][(wave * 2 + i_) * 512]); \
    }                                                                     \
  } while (0)

  STAGE(0, 0);
  __syncthreads();

#pragma unroll
  for (int it = 0; it < 5; it++) {
    int cur = it & 1;
    if (it < 4) STAGE(it + 1, cur ^ 1);  // prefetch next (drained by barrier)

    const __bf16* k_lds = kbuf[cur];
    const char* v_ldsc = (const char*)vbuf[cur];

    // additive table: one broadcast f32x4 per nr (clip-add + kills, -M0 folded)
    const float* abase = (it < 3) ? (amt_b + it * 64) : (amt_l + (it - 3) * 64);
    f32x4 ad[4];
#pragma unroll
    for (int nr = 0; nr < 4; nr++)
      ad[nr] = *(const f32x4*)(abase + nr * 16 + lgr * 4);

    // S^T = K . Q^T for both q-groups (K fragments shared)
    f32x4 sA[4], sB[4];
    __builtin_amdgcn_s_setprio(1);
#pragma unroll
    for (int nr = 0; nr < 4; nr++) {
      int row = nr * 16 + lrow;
      bf16x8 kf0 = *(const bf16x8*)((const char*)k_lds + row * 128 +
                                    ((lgr * 16) ^ ((row & 7) << 4)));
      bf16x8 kf1 = *(const bf16x8*)((const char*)k_lds + row * 128 +
                                    ((64 + lgr * 16) ^ ((row & 7) << 4)));
      f32x4 zA = f32x4{0.f, 0.f, 0.f, 0.f};
      zA = __builtin_amdgcn_mfma_f32_16x16x32_bf16(kf0, qA0, zA, 0, 0, 0);
      zA = __builtin_amdgcn_mfma_f32_16x16x32_bf16(kf1, qA1, zA, 0, 0, 0);
      sA[nr] = zA;
      f32x4 zB = f32x4{0.f, 0.f, 0.f, 0.f};
      zB = __builtin_amdgcn_mfma_f32_16x16x32_bf16(kf0, qB0, zB, 0, 0, 0);
      zB = __builtin_amdgcn_mfma_f32_16x16x32_bf16(kf1, qB1, zB, 0, 0, 0);
      sB[nr] = zB;
    }
    __builtin_amdgcn_s_setprio(0);

    // p = exp(clip(s) + add); per-lane partial sums
#pragma unroll
    for (int nr = 0; nr < 4; nr++) {
#pragma unroll
      for (int reg = 0; reg < 4; reg++) {
        float vA = fminf(fmaxf(sA[nr][reg], -10000.f), 10000.f) + ad[nr][reg];
        float pA = __expf(vA);
        sA[nr][reg] = pA;
        lA += pA;
        float vB = fminf(fmaxf(sB[nr][reg], -10000.f), 10000.f) + ad[nr][reg];
        float pB = __expf(vB);
        sB[nr][reg] = pB;
        lB += pB;
      }
    }

    // pack P -> own-lane B-fragments (formal-k permutation; NO shuffle)
    i32x4 wA0, wA1, wB0, wB1;
    wA0[0] = (int)cvtpk(sA[0][0], sA[0][1]);
    wA0[1] = (int)cvtpk(sA[0][2], sA[0][3]);
    wA0[2] = (int)cvtpk(sA[1][0], sA[1][1]);
    wA0[3] = (int)cvtpk(sA[1][2], sA[1][3]);
    wA1[0] = (int)cvtpk(sA[2][0], sA[2][1]);
    wA1[1] = (int)cvtpk(sA[2][2], sA[2][3]);
    wA1[2] = (int)cvtpk(sA[3][0], sA[3][1]);
    wA1[3] = (int)cvtpk(sA[3][2], sA[3][3]);
    wB0[0] = (int)cvtpk(sB[0][0], sB[0][1]);
    wB0[1] = (int)cvtpk(sB[0][2], sB[0][3]);
    wB0[2] = (int)cvtpk(sB[1][0], sB[1][1]);
    wB0[3] = (int)cvtpk(sB[1][2], sB[1][3]);
    wB1[0] = (int)cvtpk(sB[2][0], sB[2][1]);
    wB1[1] = (int)cvtpk(sB[2][2], sB[2][3]);
    wB1[2] = (int)cvtpk(sB[3][0], sB[3][1]);
    wB1[3] = (int)cvtpk(sB[3][2], sB[3][3]);
    bf16x8 pbA0 = __builtin_bit_cast(bf16x8, wA0);
    bf16x8 pbA1 = __builtin_bit_cast(bf16x8, wA1);
    bf16x8 pbB0 = __builtin_bit_cast(bf16x8, wB0);
    bf16x8 pbB1 = __builtin_bit_cast(bf16x8, wB1);

    // O^T += V^T . P^T  (V A-frags under sigma, shared across groups)
    __builtin_amdgcn_s_setprio(1);
#pragma unroll
    for (int nd = 0; nd < 4; nd++) {
      int row = nd * 16 + lrow;  // d index
      bf16x8 va0 = vfrag(v_ldsc, row, g0, 2 + g0, half);
      bf16x8 va1 = vfrag(v_ldsc, row, 4 + g0, 6 + g0, half);
      oA[nd] = __builtin_amdgcn_mfma_f32_16x16x32_bf16(va0, pbA0, oA[nd], 0, 0, 0);
      oA[nd] = __builtin_amdgcn_mfma_f32_16x16x32_bf16(va1, pbA1, oA[nd], 0, 0, 0);
      oB[nd] = __builtin_amdgcn_mfma_f32_16x16x32_bf16(va0, pbB0, oB[nd], 0, 0, 0);
      oB[nd] = __builtin_amdgcn_mfma_f32_16x16x32_bf16(va1, pbB1, oB[nd], 0, 0, 0);
    }
    __builtin_amdgcn_s_setprio(0);
    if (it < 4) __syncthreads();  // buffer reuse + implicit vmcnt drain
  }
#undef STAGE

  // row-sums across the 4 lanes sharing each q
  lA += __shfl_xor(lA, 16);
  lA += __shfl_xor(lA, 32);
  lB += __shfl_xor(lB, 16);
  lB += __shfl_xor(lB, 32);
  float rlA = 1.f / lA, rlB = 1.f / lB;

  // O^T C-frag: lane reg r of quadrant nd = O[d = nd*16 + lgr*4 + r][q]
  if (qrowA < LL) {
    float* obase = out + ((size_t)b * LL + qrowA) * HID + hh * HD + lgr * 4;
#pragma unroll
    for (int nd = 0; nd < 4; nd++) {
      float4 ov;
      ov.x = oA[nd][0] * rlA;
      ov.y = oA[nd][1] * rlA;
      ov.z = oA[nd][2] * rlA;
      ov.w = oA[nd][3] * rlA;
      *(float4*)(obase + nd * 16) = ov;
    }
  }
  if (qrowB < LL) {
    float* obase = out + ((size_t)b * LL + qrowB) * HID + hh * HD + lgr * 4;
#pragma unroll
    for (int nd = 0; nd < 4; nd++) {
      float4 ov;
      ov.x = oB[nd][0] * rlB;
      ov.y = oB[nd][1] * rlB;
      ov.z = oB[nd][2] * rlB;
      ov.w = oB[nd][3] * rlB;
      *(float4*)(obase + nd * 16) = ov;
    }
  }
}

extern "C" void kernel_launch(void* const* d_in, const int* in_sizes, int n_in,
                              void* d_out, int out_size, void* d_ws, size_t ws_size,
                              hipStream_t stream) {
  (void)in_sizes; (void)n_in; (void)out_size; (void)ws_size;
  const float* hs = (const float*)d_in[0];
  const float* amask = (const float*)d_in[1];
  const float* Wq = (const float*)d_in[2];
  const float* bq = (const float*)d_in[3];
  const float* Wk = (const float*)d_in[4];
  const float* bk = (const float*)d_in[5];
  const float* Wv = (const float*)d_in[6];
  const float* bv = (const float*)d_in[7];
  float* out = (float*)d_out;

  char* ws = (char*)d_ws;
  // ws layout (bytes):
  // hsb 8388608 | wtb 6291456 | qb 8388608 | kb 8388608 | vtb 8388608
  // kgb 786432 | vgb 786432 | amt 17920
  __bf16* hsb = (__bf16*)(ws);
  __bf16* wtb = (__bf16*)(ws + 8388608);
  __bf16* qb  = (__bf16*)(ws + 14680064);
  __bf16* kb  = (__bf16*)(ws + 23068672);
  __bf16* vtb = (__bf16*)(ws + 31457280);
  __bf16* kgb = (__bf16*)(ws + 39845888);
  __bf16* vgb = (__bf16*)(ws + 40632320);
  float*  amt = (float*)(ws + 41418752);

  hipLaunchKernelGGL(prep_kernel, dim3(4370), dim3(256), 0, stream,
                     hs, hsb, Wq, Wk, Wv, wtb, amask, (unsigned int*)kgb, amt);
  hipLaunchKernelGGL(qkv_gemm_kernel, dim3(8, 32, 3), dim3(256), 0, stream,
                     hsb, wtb, bq, bk, bv, qb, kb, vtb, kgb, vgb);
  hipLaunchKernelGGL(attn_kernel, dim3(17, NH, BB), dim3(256), 0, stream,
                     qb, kb, vtb, kgb, vgb, amt, out);
}

// Round 14
// 69.382 us; speedup vs baseline: 4.3499x; 4.3499x over previous
//
#include <hip/hip_runtime.h>

#define HID 1024
#define NH 16
#define HD 64
#define BB 2
#define LL 2048
#define GC 143   // number of global-summary columns
#define GP 192   // padded global columns (3 tiles of 64)
#define AMT_PER_B 2240  // 192 global slots + 16 windows * 128 local slots

typedef __attribute__((ext_vector_type(8))) __bf16 bf16x8;
typedef __attribute__((ext_vector_type(4))) float f32x4;
typedef __attribute__((ext_vector_type(4))) int i32x4;
typedef __attribute__((ext_vector_type(2))) unsigned long long u64x2;

__device__ __forceinline__ void gload_lds16(const void* g, void* l) {
  __builtin_amdgcn_global_load_lds((const __attribute__((address_space(1))) void*)g,
                                   (__attribute__((address_space(3))) void*)l, 16, 0, 0);
}

__device__ __forceinline__ unsigned int cvtpk(float lo, float hi) {
  unsigned int r;
  asm("v_cvt_pk_bf16_f32 %0, %1, %2" : "=v"(r) : "v"(lo), "v"(hi));
  return r;
}

// V^T A-fragment under the permuted formal-k: two 8B LDS reads (swizzled granules)
__device__ __forceinline__ bf16x8 vfrag(const char* vbase, int r, int gA, int gB,
                                        int half) {
  unsigned long long lo =
      *(const unsigned long long*)(vbase + r * 128 + ((gA ^ (r & 7)) << 4) + half);
  unsigned long long hi =
      *(const unsigned long long*)(vbase + r * 128 + ((gB ^ (r & 7)) << 4) + half);
  u64x2 u;
  u[0] = lo;
  u[1] = hi;
  return __builtin_bit_cast(bf16x8, u);
}

// ------- kernel 0: fused prep (cvt_hs | cvt_wt | zero+setup | amt table) -------
__global__ __launch_bounds__(256) void prep_kernel(
    const float* __restrict__ hs, __bf16* __restrict__ hsb,
    const float* __restrict__ Wq, const float* __restrict__ Wk,
    const float* __restrict__ Wv, __bf16* __restrict__ wtb,
    const float* __restrict__ amask, unsigned int* __restrict__ zbase,
    float* __restrict__ amt) {
  int bx = blockIdx.x;
  int t = threadIdx.x;
  if (bx < 2048) {
    // ---- hidden_states fp32 -> bf16 ----
    int i = bx * 256 + t;
    const float4* src = (const float4*)hs;
    float4 a = src[2 * i], b = src[2 * i + 1];
    bf16x8 v;
    v[0] = (__bf16)a.x; v[1] = (__bf16)a.y; v[2] = (__bf16)a.z; v[3] = (__bf16)a.w;
    v[4] = (__bf16)b.x; v[5] = (__bf16)b.y; v[6] = (__bf16)b.z; v[7] = (__bf16)b.w;
    ((bf16x8*)hsb)[i] = v;
  } else if (bx < 2048 + 768) {
    // ---- W [k][n] fp32 -> Wt [n][k] bf16 ----
    int z3 = bx - 2048;
    int kt = z3 & 15, nt = (z3 >> 4) & 15, z = z3 >> 8;
    const float* w = (z == 0) ? Wq : (z == 1) ? Wk : Wv;
    __bf16* dst = wtb + (size_t)z * HID * HID;
    __shared__ __bf16 tile[64][66];
    int cr = t & 63, rr = t >> 6;
#pragma unroll
    for (int it = 0; it < 16; it++) {
      int r = it * 4 + rr;
      tile[cr][r] = (__bf16)w[(size_t)(kt * 64 + r) * HID + nt * 64 + cr];
    }
    __syncthreads();
#pragma unroll
    for (int it = 0; it < 16; it++) {
      int r = it * 4 + rr;
      dst[(size_t)(nt * 64 + r) * HID + kt * 64 + cr] = tile[r][cr];
    }
  } else if (bx < 2048 + 768 + 1536) {
    // ---- zero compact K/V buffers ----
    int i = (bx - 2816) * 256 + t;  // 1536 blocks -> 393216 dwords
    zbase[i] = 0u;
  } else {
    // ---- combined additive softmax table: clip(s) + amt = ready for exp ----
    int idx = (bx - 4352) * 256 + t;
    if (idx < BB * AMT_PER_B) {
      int b = idx / AMT_PER_B, r = idx % AMT_PER_B;
      float val;
      if (r < GP) {
        int k = r / 9, j = r - 9 * k;
        val = (r < GC) ? (amask[b * LL + 120 + 128 * k + j] - 20.f) : -1e5f;
      } else {
        int r2 = r - GP;
        int w = r2 >> 7, off = r2 & 127;
        bool gcol = (off >= 120) || (off == 0 && w != 0);
        val = gcol ? -1e5f : (amask[b * LL + w * 128 + off] - 20.f);
      }
      amt[idx] = val;
    }
  }
}

// ---------------- kernel 1: QKV GEMM (bf16 MFMA, 128x128x64) ----------------
__global__ __launch_bounds__(256, 2) void qkv_gemm_kernel(
    const __bf16* __restrict__ hsb, const __bf16* __restrict__ wtb,
    const float* __restrict__ bq, const float* __restrict__ bk,
    const float* __restrict__ bv, __bf16* __restrict__ qb,
    __bf16* __restrict__ kkb, __bf16* __restrict__ vtb,
    __bf16* __restrict__ kgb, __bf16* __restrict__ vgb) {
  int nt = blockIdx.x, mt = blockIdx.y, which = blockIdx.z;
  const __bf16* wt = wtb + (size_t)which * HID * HID;
  const float* bias = (which == 0) ? bq : (which == 1) ? bk : bv;

  __shared__ __bf16 a_lds[128 * 64];
  __shared__ __bf16 b_lds[128 * 64];

  int tid = threadIdx.x;
  int wave = tid >> 6, lane = tid & 63;
  int wm = wave >> 1, wn = wave & 1;
  int lrow = lane & 15, lgr = lane >> 4, g = lane & 7;

  f32x4 acc[4][4];
#pragma unroll
  for (int i = 0; i < 4; i++)
#pragma unroll
    for (int j = 0; j < 4; j++) acc[i][j] = f32x4{0.f, 0.f, 0.f, 0.f};

  for (int kk = 0; kk < HID; kk += 64) {
#pragma unroll
    for (int i = 0; i < 4; i++) {
      int r = (wave * 4 + i) * 8 + (lane >> 3);
      int gs = (g ^ (r & 7)) * 8;
      gload_lds16(hsb + (size_t)(mt * 128 + r) * HID + kk + gs,
                  &a_lds[(wave * 4 + i) * 512]);
      gload_lds16(wt + (size_t)(nt * 128 + r) * HID + kk + gs,
                  &b_lds[(wave * 4 + i) * 512]);
    }
    __syncthreads();
#pragma unroll
    for (int kf = 0; kf < 2; kf++) {
      bf16x8 af[4], bfr[4];
#pragma unroll
      for (int mr = 0; mr < 4; mr++) {
        int row = wm * 64 + mr * 16 + lrow;
        af[mr] = *(const bf16x8*)((const char*)a_lds + row * 128 +
                                  ((kf * 64 + lgr * 16) ^ ((row & 7) << 4)));
      }
#pragma unroll
      for (int nr = 0; nr < 4; nr++) {
        int row = wn * 64 + nr * 16 + lrow;
        bfr[nr] = *(const bf16x8*)((const char*)b_lds + row * 128 +
                                   ((kf * 64 + lgr * 16) ^ ((row & 7) << 4)));
      }
#pragma unroll
      for (int mr = 0; mr < 4; mr++)
#pragma unroll
        for (int nr = 0; nr < 4; nr++)
          acc[mr][nr] = __builtin_amdgcn_mfma_f32_16x16x32_bf16(
              af[mr], bfr[nr], acc[mr][nr], 0, 0, 0);
    }
    __syncthreads();
  }

  // epilogue: bias, (Q: x0.125), scatter to per-head layouts (+ global compacts)
#pragma unroll
  for (int nr = 0; nr < 4; nr++) {
    int n = nt * 128 + wn * 64 + nr * 16 + lrow;
    float bsv = bias[n];
    int hh = n >> 6, d = n & 63;
#pragma unroll
    for (int mr = 0; mr < 4; mr++) {
#pragma unroll
      for (int reg = 0; reg < 4; reg++) {
        int m = mt * 128 + wm * 64 + mr * 16 + lgr * 4 + reg;
        int bidx = m >> 11, l = m & 2047;
        float val = acc[mr][nr][reg] + bsv;
        int c7 = l & 127;
        bool isg = (c7 >= 120) || (c7 == 0 && l != 0);
        int cidx = (c7 >= 120) ? ((l >> 7) * 9 + (c7 - 120)) : (((l >> 7) - 1) * 9 + 8);
        if (which == 0) {
          val *= 0.125f;  // fold 1/sqrt(64) into Q (exact pow2)
          qb[((size_t)(bidx * NH + hh) * LL + l) * HD + d] = (__bf16)val;
        } else if (which == 1) {
          __bf16 bv16 = (__bf16)val;
          kkb[((size_t)(bidx * NH + hh) * LL + l) * HD + d] = bv16;
          if (isg) kgb[((size_t)(bidx * NH + hh) * GP + cidx) * HD + d] = bv16;
        } else {
          __bf16 bv16 = (__bf16)val;
          vtb[((size_t)(bidx * NH + hh) * HD + d) * LL + l] = bv16;
          if (isg) vgb[((size_t)(bidx * NH + hh) * HD + d) * GP + cidx] = bv16;
        }
      }
    }
  }
}

// ---- kernel 2: attention, transposed-output, 2 q-groups/wave, ZERO-shuffle PV.
// S^T = mfma(A=K, B=Q). PV uses a permuted formal-k: sigma(lgr,e) =
// (e>>2)*16 + lgr*4 + (e&3), so each lane's own cvt_pk-packed P words ARE the
// P^T B-fragment (no bpermute); the V^T A-fragment is two ds_read_b64 per
// half. Blocks qt<16: rows [qt*128+1, qt*128+128], W=qt*128; qt==16: rows
// [0,127], W=0 (duplicated rows bitwise-identical).
__global__ __launch_bounds__(256, 4) void attn_kernel(
    const __bf16* __restrict__ qb, const __bf16* __restrict__ kkb,
    const __bf16* __restrict__ vtb, const __bf16* __restrict__ kgb,
    const __bf16* __restrict__ vgb, const float* __restrict__ amt,
    float* __restrict__ out) {
  __shared__ __bf16 kbuf[2][64 * 64];
  __shared__ __bf16 vbuf[2][64 * 64];

  int qt = blockIdx.x, hh = blockIdx.y, b = blockIdx.z;
  int tid = threadIdx.x, wave = tid >> 6, lane = tid & 63;
  int lrow = lane & 15, lgr = lane >> 4, g = lane & 7;

  const __bf16* qbh = qb + (size_t)(b * NH + hh) * LL * HD;
  const __bf16* kbh = kkb + (size_t)(b * NH + hh) * LL * HD;
  const __bf16* vth = vtb + (size_t)(b * NH + hh) * HD * LL;
  const __bf16* kgh = kgb + (size_t)(b * NH + hh) * GP * HD;
  const __bf16* vgh = vgb + (size_t)(b * NH + hh) * HD * GP;

  int shift = (qt == 16) ? 0 : 1;
  int qt2 = (qt == 16) ? 0 : qt;
  int W = qt2 * 128;
  const float* amt_b = amt + b * AMT_PER_B;
  const float* amt_l = amt_b + GP + qt2 * 128;

  int qrowA = qt2 * 128 + shift + wave * 32 + lrow;  // group A q-row
  int qrowB = qrowA + 16;                            // group B q-row
  int qldA = (qrowA > LL - 1) ? (LL - 1) : qrowA;
  int qldB = (qrowB > LL - 1) ? (LL - 1) : qrowB;
  bf16x8 qA0 = *(const bf16x8*)(qbh + (size_t)qldA * HD + lgr * 8);
  bf16x8 qA1 = *(const bf16x8*)(qbh + (size_t)qldA * HD + 32 + lgr * 8);
  bf16x8 qB0 = *(const bf16x8*)(qbh + (size_t)qldB * HD + lgr * 8);
  bf16x8 qB1 = *(const bf16x8*)(qbh + (size_t)qldB * HD + 32 + lgr * 8);

  // V-frag granule ids under sigma (fixed per lane)
  int g0 = lgr >> 1, half = (lgr & 1) * 8;

  float lA = 0.f, lB = 0.f;
  f32x4 oA[4], oB[4];
#pragma unroll
  for (int i = 0; i < 4; i++) {
    oA[i] = f32x4{0.f, 0.f, 0.f, 0.f};
    oB[i] = f32x4{0.f, 0.f, 0.f, 0.f};
  }

#define STAGE(IT, BI)                                                     \
  do {                                                                    \
    const __bf16 *ks_, *vs_;                                              \
    int vst_;                                                             \
    if ((IT) < 3) {                                                       \
      ks_ = kgh + (size_t)((IT)*64) * HD;                                 \
      vs_ = vgh + (IT)*64;                                                \
      vst_ = GP;                                                          \
    } else {                                                              \
      int cb_ = W + ((IT)-3) * 64;                                        \
      ks_ = kbh + (size_t)cb_ * HD;                                       \
      vs_ = vth + cb_;                                                    \
      vst_ = LL;                                                          \
    }                                                                     \
    _Pragma("unroll")                                                     \
    for (int i_ = 0; i_ < 2; i_++) {                                      \
      int r_ = (wave * 2 + i_) * 8 + (lane >> 3);                         \
      int gs_ = (g ^ (r_ & 7)) * 8;                                       \
      gload_lds16(ks_ + (size_t)r_ * HD + gs_, &kbuf[BI][(wave * 2 + i_) * 512]); \
      gload_lds16(vs_ + (size_t)r_ * vst_ + gs_, &vbuf[BI][(wave * 2 + i_) * 512]); \
    }                                                                     \
  } while (0)

  STAGE(0, 0);
  __syncthreads();

#pragma unroll
  for (int it = 0; it < 5; it++) {
    int cur = it & 1;
    if (it < 4) STAGE(it + 1, cur ^ 1);  // prefetch next (drained by barrier)

    const __bf16* k_lds = kbuf[cur];
    const char* v_ldsc = (const char*)vbuf[cur];

    // additive table: one broadcast f32x4 per nr (clip-add + kills, -M0 folded)
    const float* abase = (it < 3) ? (amt_b + it * 64) : (amt_l + (it - 3) * 64);
    f32x4 ad[4];
#pragma unroll
    for (int nr = 0; nr < 4; nr++)
      ad[nr] = *(const f32x4*)(abase + nr * 16 + lgr * 4);

    // S^T = K . Q^T for both q-groups (K fragments shared)
    f32x4 sA[4], sB[4];
    __builtin_amdgcn_s_setprio(1);
#pragma unroll
    for (int nr = 0; nr < 4; nr++) {
      int row = nr * 16 + lrow;
      bf16x8 kf0 = *(const bf16x8*)((const char*)k_lds + row * 128 +
                                    ((lgr * 16) ^ ((row & 7) << 4)));
      bf16x8 kf1 = *(const bf16x8*)((const char*)k_lds + row * 128 +
                                    ((64 + lgr * 16) ^ ((row & 7) << 4)));
      f32x4 zA = f32x4{0.f, 0.f, 0.f, 0.f};
      zA = __builtin_amdgcn_mfma_f32_16x16x32_bf16(kf0, qA0, zA, 0, 0, 0);
      zA = __builtin_amdgcn_mfma_f32_16x16x32_bf16(kf1, qA1, zA, 0, 0, 0);
      sA[nr] = zA;
      f32x4 zB = f32x4{0.f, 0.f, 0.f, 0.f};
      zB = __builtin_amdgcn_mfma_f32_16x16x32_bf16(kf0, qB0, zB, 0, 0, 0);
      zB = __builtin_amdgcn_mfma_f32_16x16x32_bf16(kf1, qB1, zB, 0, 0, 0);
      sB[nr] = zB;
    }
    __builtin_amdgcn_s_setprio(0);

    // p = exp(clip(s) + add); per-lane partial sums
#pragma unroll
    for (int nr = 0; nr < 4; nr++) {
#pragma unroll
      for (int reg = 0; reg < 4; reg++) {
        float vA = fminf(fmaxf(sA[nr][reg], -10000.f), 10000.f) + ad[nr][reg];
        float pA = __expf(vA);
        sA[nr][reg] = pA;
        lA += pA;
        float vB = fminf(fmaxf(sB[nr][reg], -10000.f), 10000.f) + ad[nr][reg];
        float pB = __expf(vB);
        sB[nr][reg] = pB;
        lB += pB;
      }
    }

    // pack P -> own-lane B-fragments (formal-k permutation; NO shuffle)
    i32x4 wA0, wA1, wB0, wB1;
    wA0[0] = (int)cvtpk(sA[0][0], sA[0][1]);
    wA0[1] = (int)cvtpk(sA[0][2], sA[0][3]);
    wA0[2] = (int)cvtpk(sA[1][0], sA[1][1]);
    wA0[3] = (int)cvtpk(sA[1][2], sA[1][3]);
    wA1[0] = (int)cvtpk(sA[2][0], sA[2][1]);
    wA1[1] = (int)cvtpk(sA[2][2], sA[2][3]);
    wA1[2] = (int)cvtpk(sA[3][0], sA[3][1]);
    wA1[3] = (int)cvtpk(sA[3][2], sA[3][3]);
    wB0[0] = (int)cvtpk(sB[0][0], sB[0][1]);
    wB0[1] = (int)cvtpk(sB[0][2], sB[0][3]);
    wB0[2] = (int)cvtpk(sB[1][0], sB[1][1]);
    wB0[3] = (int)cvtpk(sB[1][2], sB[1][3]);
    wB1[0] = (int)cvtpk(sB[2][0], sB[2][1]);
    wB1[1] = (int)cvtpk(sB[2][2], sB[2][3]);
    wB1[2] = (int)cvtpk(sB[3][0], sB[3][1]);
    wB1[3] = (int)cvtpk(sB[3][2], sB[3][3]);
    bf16x8 pbA0 = __builtin_bit_cast(bf16x8, wA0);
    bf16x8 pbA1 = __builtin_bit_cast(bf16x8, wA1);
    bf16x8 pbB0 = __builtin_bit_cast(bf16x8, wB0);
    bf16x8 pbB1 = __builtin_bit_cast(bf16x8, wB1);

    // O^T += V^T . P^T  (V A-frags under sigma, shared across groups)
    __builtin_amdgcn_s_setprio(1);
#pragma unroll
    for (int nd = 0; nd < 4; nd++) {
      int row = nd * 16 + lrow;  // d index
      bf16x8 va0 = vfrag(v_ldsc, row, g0, 2 + g0, half);
      bf16x8 va1 = vfrag(v_ldsc, row, 4 + g0, 6 + g0, half);
      oA[nd] = __builtin_amdgcn_mfma_f32_16x16x32_bf16(va0, pbA0, oA[nd], 0, 0, 0);
      oA[nd] = __builtin_amdgcn_mfma_f32_16x16x32_bf16(va1, pbA1, oA[nd], 0, 0, 0);
      oB[nd] = __builtin_amdgcn_mfma_f32_16x16x32_bf16(va0, pbB0, oB[nd], 0, 0, 0);
      oB[nd] = __builtin_amdgcn_mfma_f32_16x16x32_bf16(va1, pbB1, oB[nd], 0, 0, 0);
    }
    __builtin_amdgcn_s_setprio(0);
    if (it < 4) __syncthreads();  // buffer reuse + implicit vmcnt drain
  }
#undef STAGE

  // row-sums across the 4 lanes sharing each q
  lA += __shfl_xor(lA, 16);
  lA += __shfl_xor(lA, 32);
  lB += __shfl_xor(lB, 16);
  lB += __shfl_xor(lB, 32);
  float rlA = 1.f / lA, rlB = 1.f / lB;

  // O^T C-frag: lane reg r of quadrant nd = O[d = nd*16 + lgr*4 + r][q]
  if (qrowA < LL) {
    float* obase = out + ((size_t)b * LL + qrowA) * HID + hh * HD + lgr * 4;
#pragma unroll
    for (int nd = 0; nd < 4; nd++) {
      float4 ov;
      ov.x = oA[nd][0] * rlA;
      ov.y = oA[nd][1] * rlA;
      ov.z = oA[nd][2] * rlA;
      ov.w = oA[nd][3] * rlA;
      *(float4*)(obase + nd * 16) = ov;
    }
  }
  if (qrowB < LL) {
    float* obase = out + ((size_t)b * LL + qrowB) * HID + hh * HD + lgr * 4;
#pragma unroll
    for (int nd = 0; nd < 4; nd++) {
      float4 ov;
      ov.x = oB[nd][0] * rlB;
      ov.y = oB[nd][1] * rlB;
      ov.z = oB[nd][2] * rlB;
      ov.w = oB[nd][3] * rlB;
      *(float4*)(obase + nd * 16) = ov;
    }
  }
}

extern "C" void kernel_launch(void* const* d_in, const int* in_sizes, int n_in,
                              void* d_out, int out_size, void* d_ws, size_t ws_size,
                              hipStream_t stream) {
  (void)in_sizes; (void)n_in; (void)out_size; (void)ws_size;
  const float* hs = (const float*)d_in[0];
  const float* amask = (const float*)d_in[1];
  const float* Wq = (const float*)d_in[2];
  const float* bq = (const float*)d_in[3];
  const float* Wk = (const float*)d_in[4];
  const float* bk = (const float*)d_in[5];
  const float* Wv = (const float*)d_in[6];
  const float* bv = (const float*)d_in[7];
  float* out = (float*)d_out;

  char* ws = (char*)d_ws;
  // ws layout (bytes):
  // hsb 8388608 | wtb 6291456 | qb 8388608 | kb 8388608 | vtb 8388608
  // kgb 786432 | vgb 786432 | amt 17920
  __bf16* hsb = (__bf16*)(ws);
  __bf16* wtb = (__bf16*)(ws + 8388608);
  __bf16* qb  = (__bf16*)(ws + 14680064);
  __bf16* kb  = (__bf16*)(ws + 23068672);
  __bf16* vtb = (__bf16*)(ws + 31457280);
  __bf16* kgb = (__bf16*)(ws + 39845888);
  __bf16* vgb = (__bf16*)(ws + 40632320);
  float*  amt = (float*)(ws + 41418752);

  hipLaunchKernelGGL(prep_kernel, dim3(4370), dim3(256), 0, stream,
                     hs, hsb, Wq, Wk, Wv, wtb, amask, (unsigned int*)kgb, amt);
  hipLaunchKernelGGL(qkv_gemm_kernel, dim3(8, 32, 3), dim3(256), 0, stream,
                     hsb, wtb, bq, bk, bv, qb, kb, vtb, kgb, vgb);
  hipLaunchKernelGGL(attn_kernel, dim3(17, NH, BB), dim3(256), 0, stream,
                     qb, kb, vtb, kgb, vgb, amt, out);
}

// Round 15
// 64.787 us; speedup vs baseline: 4.6584x; 1.0709x over previous
//
#include <hip/hip_runtime.h>

#define HID 1024
#define NH 16
#define HD 64
#define BB 2
#define LL 2048
#define GC 143   // number of global-summary columns
#define GP 192   // padded global columns (3 tiles of 64)
#define AMT_PER_B 2240  // 192 global slots + 16 windows * 128 local slots

typedef __attribute__((ext_vector_type(8))) __bf16 bf16x8;
typedef __attribute__((ext_vector_type(4))) __bf16 bf16x4;
typedef __attribute__((ext_vector_type(4))) float f32x4;
typedef __attribute__((ext_vector_type(4))) int i32x4;
typedef __attribute__((ext_vector_type(2))) unsigned long long u64x2;

__device__ __forceinline__ void gload_lds16(const void* g, void* l) {
  __builtin_amdgcn_global_load_lds((const __attribute__((address_space(1))) void*)g,
                                   (__attribute__((address_space(3))) void*)l, 16, 0, 0);
}

__device__ __forceinline__ unsigned int cvtpk(float lo, float hi) {
  unsigned int r;
  asm("v_cvt_pk_bf16_f32 %0, %1, %2" : "=v"(r) : "v"(lo), "v"(hi));
  return r;
}

// V^T A-fragment under the permuted formal-k: two 8B LDS reads (swizzled granules)
__device__ __forceinline__ bf16x8 vfrag(const char* vbase, int r, int gA, int gB,
                                        int half) {
  unsigned long long lo =
      *(const unsigned long long*)(vbase + r * 128 + ((gA ^ (r & 7)) << 4) + half);
  unsigned long long hi =
      *(const unsigned long long*)(vbase + r * 128 + ((gB ^ (r & 7)) << 4) + half);
  u64x2 u;
  u[0] = lo;
  u[1] = hi;
  return __builtin_bit_cast(bf16x8, u);
}

// ------- kernel 0: fused prep (cvt_hs | cvt_wt | zero+setup | amt table) -------
__global__ __launch_bounds__(256) void prep_kernel(
    const float* __restrict__ hs, __bf16* __restrict__ hsb,
    const float* __restrict__ Wq, const float* __restrict__ Wk,
    const float* __restrict__ Wv, __bf16* __restrict__ wtb,
    const float* __restrict__ amask, unsigned int* __restrict__ zbase,
    float* __restrict__ amt) {
  int bx = blockIdx.x;
  int t = threadIdx.x;
  if (bx < 2048) {
    // ---- hidden_states fp32 -> bf16 ----
    int i = bx * 256 + t;
    const float4* src = (const float4*)hs;
    float4 a = src[2 * i], b = src[2 * i + 1];
    bf16x8 v;
    v[0] = (__bf16)a.x; v[1] = (__bf16)a.y; v[2] = (__bf16)a.z; v[3] = (__bf16)a.w;
    v[4] = (__bf16)b.x; v[5] = (__bf16)b.y; v[6] = (__bf16)b.z; v[7] = (__bf16)b.w;
    ((bf16x8*)hsb)[i] = v;
  } else if (bx < 2048 + 768) {
    // ---- W [k][n] fp32 -> Wt [n][k] bf16 ----
    int z3 = bx - 2048;
    int kt = z3 & 15, nt = (z3 >> 4) & 15, z = z3 >> 8;
    const float* w = (z == 0) ? Wq : (z == 1) ? Wk : Wv;
    __bf16* dst = wtb + (size_t)z * HID * HID;
    __shared__ __bf16 tile[64][66];
    int cr = t & 63, rr = t >> 6;
#pragma unroll
    for (int it = 0; it < 16; it++) {
      int r = it * 4 + rr;
      tile[cr][r] = (__bf16)w[(size_t)(kt * 64 + r) * HID + nt * 64 + cr];
    }
    __syncthreads();
#pragma unroll
    for (int it = 0; it < 16; it++) {
      int r = it * 4 + rr;
      dst[(size_t)(nt * 64 + r) * HID + kt * 64 + cr] = tile[r][cr];
    }
  } else if (bx < 2048 + 768 + 1536) {
    // ---- zero compact K/V buffers ----
    int i = (bx - 2816) * 256 + t;  // 1536 blocks -> 393216 dwords
    zbase[i] = 0u;
  } else {
    // ---- combined additive softmax table: clip(s) + amt = ready for exp ----
    int idx = (bx - 4352) * 256 + t;
    if (idx < BB * AMT_PER_B) {
      int b = idx / AMT_PER_B, r = idx % AMT_PER_B;
      float val;
      if (r < GP) {
        int k = r / 9, j = r - 9 * k;
        val = (r < GC) ? (amask[b * LL + 120 + 128 * k + j] - 20.f) : -1e5f;
      } else {
        int r2 = r - GP;
        int w = r2 >> 7, off = r2 & 127;
        bool gcol = (off >= 120) || (off == 0 && w != 0);
        val = gcol ? -1e5f : (amask[b * LL + w * 128 + off] - 20.f);
      }
      amt[idx] = val;
    }
  }
}

// ---------------- kernel 1: QKV GEMM (bf16 MFMA, 128x128x64) ----------------
// XCD-aware block swizzle (256 blocks per which; 256%8==0 -> bijective):
// each XCD owns 4 consecutive mt panels x all nt -> A/B panels stay L2-local.
__global__ __launch_bounds__(256, 2) void qkv_gemm_kernel(
    const __bf16* __restrict__ hsb, const __bf16* __restrict__ wtb,
    const float* __restrict__ bq, const float* __restrict__ bk,
    const float* __restrict__ bv, __bf16* __restrict__ qb,
    __bf16* __restrict__ kkb, __bf16* __restrict__ vtb,
    __bf16* __restrict__ kgb, __bf16* __restrict__ vgb) {
  int f = blockIdx.x + (blockIdx.y << 3);    // 0..255 within z-plane
  int wsw = ((f & 7) << 5) + (f >> 3);       // XCD-contiguous work id
  int nt = wsw & 7, mt = wsw >> 3, which = blockIdx.z;
  const __bf16* wt = wtb + (size_t)which * HID * HID;
  const float* bias = (which == 0) ? bq : (which == 1) ? bk : bv;

  __shared__ __bf16 a_lds[128 * 64];
  __shared__ __bf16 b_lds[128 * 64];

  int tid = threadIdx.x;
  int wave = tid >> 6, lane = tid & 63;
  int wm = wave >> 1, wn = wave & 1;
  int lrow = lane & 15, lgr = lane >> 4, g = lane & 7;

  f32x4 acc[4][4];
#pragma unroll
  for (int i = 0; i < 4; i++)
#pragma unroll
    for (int j = 0; j < 4; j++) acc[i][j] = f32x4{0.f, 0.f, 0.f, 0.f};

  for (int kk = 0; kk < HID; kk += 64) {
#pragma unroll
    for (int i = 0; i < 4; i++) {
      int r = (wave * 4 + i) * 8 + (lane >> 3);
      int gs = (g ^ (r & 7)) * 8;
      gload_lds16(hsb + (size_t)(mt * 128 + r) * HID + kk + gs,
                  &a_lds[(wave * 4 + i) * 512]);
      gload_lds16(wt + (size_t)(nt * 128 + r) * HID + kk + gs,
                  &b_lds[(wave * 4 + i) * 512]);
    }
    __syncthreads();
#pragma unroll
    for (int kf = 0; kf < 2; kf++) {
      bf16x8 af[4], bfr[4];
#pragma unroll
      for (int mr = 0; mr < 4; mr++) {
        int row = wm * 64 + mr * 16 + lrow;
        af[mr] = *(const bf16x8*)((const char*)a_lds + row * 128 +
                                  ((kf * 64 + lgr * 16) ^ ((row & 7) << 4)));
      }
#pragma unroll
      for (int nr = 0; nr < 4; nr++) {
        int row = wn * 64 + nr * 16 + lrow;
        bfr[nr] = *(const bf16x8*)((const char*)b_lds + row * 128 +
                                   ((kf * 64 + lgr * 16) ^ ((row & 7) << 4)));
      }
#pragma unroll
      for (int mr = 0; mr < 4; mr++)
#pragma unroll
        for (int nr = 0; nr < 4; nr++)
          acc[mr][nr] = __builtin_amdgcn_mfma_f32_16x16x32_bf16(
              af[mr], bfr[nr], acc[mr][nr], 0, 0, 0);
    }
    __syncthreads();
  }

  // epilogue: bias, (Q: x0.125), scatter to per-head layouts (+ global compacts)
  if (which != 2) {
#pragma unroll
    for (int nr = 0; nr < 4; nr++) {
      int n = nt * 128 + wn * 64 + nr * 16 + lrow;
      float bsv = bias[n];
      int hh = n >> 6, d = n & 63;
#pragma unroll
      for (int mr = 0; mr < 4; mr++) {
#pragma unroll
        for (int reg = 0; reg < 4; reg++) {
          int m = mt * 128 + wm * 64 + mr * 16 + lgr * 4 + reg;
          int bidx = m >> 11, l = m & 2047;
          float val = acc[mr][nr][reg] + bsv;
          int c7 = l & 127;
          bool isg = (c7 >= 120) || (c7 == 0 && l != 0);
          int cidx = (c7 >= 120) ? ((l >> 7) * 9 + (c7 - 120)) : (((l >> 7) - 1) * 9 + 8);
          if (which == 0) {
            val *= 0.125f;  // fold 1/sqrt(64) into Q (exact pow2)
            qb[((size_t)(bidx * NH + hh) * LL + l) * HD + d] = (__bf16)val;
          } else {
            __bf16 bv16 = (__bf16)val;
            kkb[((size_t)(bidx * NH + hh) * LL + l) * HD + d] = bv16;
            if (isg) kgb[((size_t)(bidx * NH + hh) * GP + cidx) * HD + d] = bv16;
          }
        }
      }
    }
  } else {
    // V epilogue: vtb[d][l] -- per-thread reg axis is contiguous in l,
    // so pack 4 bf16 and store 8B at a time (identical bytes, 1/4 the stores)
    int bidx = mt >> 4;  // constant per block (m never crosses the 2048 bound)
#pragma unroll
    for (int nr = 0; nr < 4; nr++) {
      int n = nt * 128 + wn * 64 + nr * 16 + lrow;
      float bsv = bias[n];
      int hh = n >> 6, d = n & 63;
      size_t bh = (size_t)(bidx * NH + hh);
#pragma unroll
      for (int mr = 0; mr < 4; mr++) {
        int l0 = (mt * 128 + wm * 64 + mr * 16 + lgr * 4) & 2047;
        bf16x4 pv;
#pragma unroll
        for (int reg = 0; reg < 4; reg++) pv[reg] = (__bf16)(acc[mr][nr][reg] + bsv);
        *(bf16x4*)(vtb + (bh * HD + d) * LL + l0) = pv;
#pragma unroll
        for (int reg = 0; reg < 4; reg++) {
          int l = l0 + reg;
          int c7 = l & 127;
          bool isg = (c7 >= 120) || (c7 == 0 && l != 0);
          if (isg) {
            int cidx = (c7 >= 120) ? ((l >> 7) * 9 + (c7 - 120))
                                   : (((l >> 7) - 1) * 9 + 8);
            vgb[(bh * HD + d) * GP + cidx] = pv[reg];
          }
        }
      }
    }
  }
}

// ---- kernel 2: attention, transposed-output, 2 q-groups/wave, ZERO-shuffle PV.
// S^T = mfma(A=K, B=Q). PV uses a permuted formal-k: sigma(lgr,e) =
// (e>>2)*16 + lgr*4 + (e&3), so each lane's own cvt_pk-packed P words ARE the
// P^T B-fragment (no bpermute); the V^T A-fragment is two ds_read_b64 per
// half. Blocks qt<16: rows [qt*128+1, qt*128+128], W=qt*128; qt==16: rows
// [0,127], W=0 (duplicated rows bitwise-identical).
__global__ __launch_bounds__(256, 4) void attn_kernel(
    const __bf16* __restrict__ qb, const __bf16* __restrict__ kkb,
    const __bf16* __restrict__ vtb, const __bf16* __restrict__ kgb,
    const __bf16* __restrict__ vgb, const float* __restrict__ amt,
    float* __restrict__ out) {
  __shared__ __bf16 kbuf[2][64 * 64];
  __shared__ __bf16 vbuf[2][64 * 64];

  int qt = blockIdx.x, hh = blockIdx.y, b = blockIdx.z;
  int tid = threadIdx.x, wave = tid >> 6, lane = tid & 63;
  int lrow = lane & 15, lgr = lane >> 4, g = lane & 7;

  const __bf16* qbh = qb + (size_t)(b * NH + hh) * LL * HD;
  const __bf16* kbh = kkb + (size_t)(b * NH + hh) * LL * HD;
  const __bf16* vth = vtb + (size_t)(b * NH + hh) * HD * LL;
  const __bf16* kgh = kgb + (size_t)(b * NH + hh) * GP * HD;
  const __bf16* vgh = vgb + (size_t)(b * NH + hh) * HD * GP;

  int shift = (qt == 16) ? 0 : 1;
  int qt2 = (qt == 16) ? 0 : qt;
  int W = qt2 * 128;
  const float* amt_b = amt + b * AMT_PER_B;
  const float* amt_l = amt_b + GP + qt2 * 128;

  int qrowA = qt2 * 128 + shift + wave * 32 + lrow;  // group A q-row
  int qrowB = qrowA + 16;                            // group B q-row
  int qldA = (qrowA > LL - 1) ? (LL - 1) : qrowA;
  int qldB = (qrowB > LL - 1) ? (LL - 1) : qrowB;
  bf16x8 qA0 = *(const bf16x8*)(qbh + (size_t)qldA * HD + lgr * 8);
  bf16x8 qA1 = *(const bf16x8*)(qbh + (size_t)qldA * HD + 32 + lgr * 8);
  bf16x8 qB0 = *(const bf16x8*)(qbh + (size_t)qldB * HD + lgr * 8);
  bf16x8 qB1 = *(const bf16x8*)(qbh + (size_t)qldB * HD + 32 + lgr * 8);

  // V-frag granule ids under sigma (fixed per lane)
  int g0 = lgr >> 1, half = (lgr & 1) * 8;

  float lA = 0.f, lB = 0.f;
  f32x4 oA[4], oB[4];
#pragma unroll
  for (int i = 0; i < 4; i++) {
    oA[i] = f32x4{0.f, 0.f, 0.f, 0.f};
    oB[i] = f32x4{0.f, 0.f, 0.f, 0.f};
  }

#define STAGE(IT, BI)                                                     \
  do {                                                                    \
    const __bf16 *ks_, *vs_;                                              \
    int vst_;                                                             \
    if ((IT) < 3) {                                                       \
      ks_ = kgh + (size_t)((IT)*64) * HD;                                 \
      vs_ = vgh + (IT)*64;                                                \
      vst_ = GP;                                                          \
    } else {                                                              \
      int cb_ = W + ((IT)-3) * 64;                                        \
      ks_ = kbh + (size_t)cb_ * HD;                                       \
      vs_ = vth + cb_;                                                    \
      vst_ = LL;                                                          \
    }                                                                     \
    _Pragma("unroll")                                                     \
    for (int i_ = 0; i_ < 2; i_++) {                                      \
      int r_ = (wave * 2 + i_) * 8 + (lane >> 3);                         \
      int gs_ = (g ^ (r_ & 7)) * 8;                                       \
      gload_lds16(ks_ + (size_t)r_ * HD + gs_, &kbuf[BI][(wave * 2 + i_) * 512]); \
      gload_lds16(vs_ + (size_t)r_ * vst_ + gs_, &vbuf[BI][(wave * 2 + i_) * 512]); \
    }                                                                     \
  } while (0)

  STAGE(0, 0);
  __syncthreads();

#pragma unroll
  for (int it = 0; it < 5; it++) {
    int cur = it & 1;
    if (it < 4) STAGE(it + 1, cur ^ 1);  // prefetch next (drained by barrier)

    const __bf16* k_lds = kbuf[cur];
    const char* v_ldsc = (const char*)vbuf[cur];

    // additive table: one broadcast f32x4 per nr (clip-add + kills, -M0 folded)
    const float* abase = (it < 3) ? (amt_b + it * 64) : (amt_l + (it - 3) * 64);
    f32x4 ad[4];
#pragma unroll
    for (int nr = 0; nr < 4; nr++)
      ad[nr] = *(const f32x4*)(abase + nr * 16 + lgr * 4);

    // S^T = K . Q^T for both q-groups (K fragments shared)
    f32x4 sA[4], sB[4];
    __builtin_amdgcn_s_setprio(1);
#pragma unroll
    for (int nr = 0; nr < 4; nr++) {
      int row = nr * 16 + lrow;
      bf16x8 kf0 = *(const bf16x8*)((const char*)k_lds + row * 128 +
                                    ((lgr * 16) ^ ((row & 7) << 4)));
      bf16x8 kf1 = *(const bf16x8*)((const char*)k_lds + row * 128 +
                                    ((64 + lgr * 16) ^ ((row & 7) << 4)));
      f32x4 zA = f32x4{0.f, 0.f, 0.f, 0.f};
      zA = __builtin_amdgcn_mfma_f32_16x16x32_bf16(kf0, qA0, zA, 0, 0, 0);
      zA = __builtin_amdgcn_mfma_f32_16x16x32_bf16(kf1, qA1, zA, 0, 0, 0);
      sA[nr] = zA;
      f32x4 zB = f32x4{0.f, 0.f, 0.f, 0.f};
      zB = __builtin_amdgcn_mfma_f32_16x16x32_bf16(kf0, qB0, zB, 0, 0, 0);
      zB = __builtin_amdgcn_mfma_f32_16x16x32_bf16(kf1, qB1, zB, 0, 0, 0);
      sB[nr] = zB;
    }
    __builtin_amdgcn_s_setprio(0);

    // p = exp(clip(s) + add); per-lane partial sums
#pragma unroll
    for (int nr = 0; nr < 4; nr++) {
#pragma unroll
      for (int reg = 0; reg < 4; reg++) {
        float vA = fminf(fmaxf(sA[nr][reg], -10000.f), 10000.f) + ad[nr][reg];
        float pA = __expf(vA);
        sA[nr][reg] = pA;
        lA += pA;
        float vB = fminf(fmaxf(sB[nr][reg], -10000.f), 10000.f) + ad[nr][reg];
        float pB = __expf(vB);
        sB[nr][reg] = pB;
        lB += pB;
      }
    }

    // pack P -> own-lane B-fragments (formal-k permutation; NO shuffle)
    i32x4 wA0, wA1, wB0, wB1;
    wA0[0] = (int)cvtpk(sA[0][0], sA[0][1]);
    wA0[1] = (int)cvtpk(sA[0][2], sA[0][3]);
    wA0[2] = (int)cvtpk(sA[1][0], sA[1][1]);
    wA0[3] = (int)cvtpk(sA[1][2], sA[1][3]);
    wA1[0] = (int)cvtpk(sA[2][0], sA[2][1]);
    wA1[1] = (int)cvtpk(sA[2][2], sA[2][3]);
    wA1[2] = (int)cvtpk(sA[3][0], sA[3][1]);
    wA1[3] = (int)cvtpk(sA[3][2], sA[3][3]);
    wB0[0] = (int)cvtpk(sB[0][0], sB[0][1]);
    wB0[1] = (int)cvtpk(sB[0][2], sB[0][3]);
    wB0[2] = (int)cvtpk(sB[1][0], sB[1][1]);
    wB0[3] = (int)cvtpk(sB[1][2], sB[1][3]);
    wB1[0] = (int)cvtpk(sB[2][0], sB[2][1]);
    wB1[1] = (int)cvtpk(sB[2][2], sB[2][3]);
    wB1[2] = (int)cvtpk(sB[3][0], sB[3][1]);
    wB1[3] = (int)cvtpk(sB[3][2], sB[3][3]);
    bf16x8 pbA0 = __builtin_bit_cast(bf16x8, wA0);
    bf16x8 pbA1 = __builtin_bit_cast(bf16x8, wA1);
    bf16x8 pbB0 = __builtin_bit_cast(bf16x8, wB0);
    bf16x8 pbB1 = __builtin_bit_cast(bf16x8, wB1);

    // O^T += V^T . P^T  (V A-frags under sigma, shared across groups)
    __builtin_amdgcn_s_setprio(1);
#pragma unroll
    for (int nd = 0; nd < 4; nd++) {
      int row = nd * 16 + lrow;  // d index
      bf16x8 va0 = vfrag(v_ldsc, row, g0, 2 + g0, half);
      bf16x8 va1 = vfrag(v_ldsc, row, 4 + g0, 6 + g0, half);
      oA[nd] = __builtin_amdgcn_mfma_f32_16x16x32_bf16(va0, pbA0, oA[nd], 0, 0, 0);
      oA[nd] = __builtin_amdgcn_mfma_f32_16x16x32_bf16(va1, pbA1, oA[nd], 0, 0, 0);
      oB[nd] = __builtin_amdgcn_mfma_f32_16x16x32_bf16(va0, pbB0, oB[nd], 0, 0, 0);
      oB[nd] = __builtin_amdgcn_mfma_f32_16x16x32_bf16(va1, pbB1, oB[nd], 0, 0, 0);
    }
    __builtin_amdgcn_s_setprio(0);
    if (it < 4) __syncthreads();  // buffer reuse + implicit vmcnt drain
  }
#undef STAGE

  // row-sums across the 4 lanes sharing each q
  lA += __shfl_xor(lA, 16);
  lA += __shfl_xor(lA, 32);
  lB += __shfl_xor(lB, 16);
  lB += __shfl_xor(lB, 32);
  float rlA = 1.f / lA, rlB = 1.f / lB;

  // O^T C-frag: lane reg r of quadrant nd = O[d = nd*16 + lgr*4 + r][q]
  if (qrowA < LL) {
    float* obase = out + ((size_t)b * LL + qrowA) * HID + hh * HD + lgr * 4;
#pragma unroll
    for (int nd = 0; nd < 4; nd++) {
      float4 ov;
      ov.x = oA[nd][0] * rlA;
      ov.y = oA[nd][1] * rlA;
      ov.z = oA[nd][2] * rlA;
      ov.w = oA[nd][3] * rlA;
      *(float4*)(obase + nd * 16) = ov;
    }
  }
  if (qrowB < LL) {
    float* obase = out + ((size_t)b * LL + qrowB) * HID + hh * HD + lgr * 4;
#pragma unroll
    for (int nd = 0; nd < 4; nd++) {
      float4 ov;
      ov.x = oB[nd][0] * rlB;
      ov.y = oB[nd][1] * rlB;
      ov.z = oB[nd][2] * rlB;
      ov.w = oB[nd][3] * rlB;
      *(float4*)(obase + nd * 16) = ov;
    }
  }
}

extern "C" void kernel_launch(void* const* d_in, const int* in_sizes, int n_in,
                              void* d_out, int out_size, void* d_ws, size_t ws_size,
                              hipStream_t stream) {
  (void)in_sizes; (void)n_in; (void)out_size; (void)ws_size;
  const float* hs = (const float*)d_in[0];
  const float* amask = (const float*)d_in[1];
  const float* Wq = (const float*)d_in[2];
  const float* bq = (const float*)d_in[3];
  const float* Wk = (const float*)d_in[4];
  const float* bk = (const float*)d_in[5];
  const float* Wv = (const float*)d_in[6];
  const float* bv = (const float*)d_in[7];
  float* out = (float*)d_out;

  char* ws = (char*)d_ws;
  // ws layout (bytes):
  // hsb 8388608 | wtb 6291456 | qb 8388608 | kb 8388608 | vtb 8388608
  // kgb 786432 | vgb 786432 | amt 17920
  __bf16* hsb = (__bf16*)(ws);
  __bf16* wtb = (__bf16*)(ws + 8388608);
  __bf16* qb  = (__bf16*)(ws + 14680064);
  __bf16* kb  = (__bf16*)(ws + 23068672);
  __bf16* vtb = (__bf16*)(ws + 31457280);
  __bf16* kgb = (__bf16*)(ws + 39845888);
  __bf16* vgb = (__bf16*)(ws + 40632320);
  float*  amt = (float*)(ws + 41418752);

  hipLaunchKernelGGL(prep_kernel, dim3(4370), dim3(256), 0, stream,
                     hs, hsb, Wq, Wk, Wv, wtb, amask, (unsigned int*)kgb, amt);
  hipLaunchKernelGGL(qkv_gemm_kernel, dim3(8, 32, 3), dim3(256), 0, stream,
                     hsb, wtb, bq, bk, bv, qb, kb, vtb, kgb, vgb);
  hipLaunchKernelGGL(attn_kernel, dim3(17, NH, BB), dim3(256), 0, stream,
                     qb, kb, vtb, kgb, vgb, amt, out);
}